// Round 10
// baseline (454.778 us; speedup 1.0000x reference)
//
#include <hip/hip_runtime.h>

// MicrotubuleDynamicsModel fused forward, round 10:
//  - 24-plane LDS h-mirror (19968B -> 8 blocks/CU, 16 waves), deferred schedule
//    holding ONE acc (peak VGPR ~115, fits the (128,2) cap without spill)
//  - encoder and decoder fully in-register (v_permlane32_swap_b32 D->B frag
//    conversion); decoder-1+2 fused per-ot, y-frags consumed immediately
//  - x state = split bf16 pair in regs; aggregate-after-multiply GCN gather

typedef __attribute__((ext_vector_type(2)))  float  f32x2;
typedef __attribute__((ext_vector_type(4)))  float  f32x4;
typedef __attribute__((ext_vector_type(16))) float  f32x16;
typedef __attribute__((ext_vector_type(8)))  __bf16 bf16x8;
typedef __attribute__((ext_vector_type(4)))  unsigned int u32x4;

#define MFMA(a, b, c) __builtin_amdgcn_mfma_f32_32x32x16_bf16((a), (b), (c), 0, 0, 0)

#define QSTR 52          // node slots per quad-plane (no pad; conflicts identical)
#define QP   (QSTR * 4)  // dwords per quad-plane = 208

struct bfpair { __bf16 h, l; };
__device__ __forceinline__ bfpair splitf(float f) {
    bfpair p;
    p.h = (__bf16)f;               // RTN
    p.l = (__bf16)(f - (float)p.h);
    return p;
}
__device__ __forceinline__ unsigned pk2(__bf16 a, __bf16 b) {
    return (unsigned)__builtin_bit_cast(unsigned short, a)
         | ((unsigned)__builtin_bit_cast(unsigned short, b) << 16);
}

// D-layout k-chunk (regs RB..RB+7 of a 32x32 D tile) -> B-frag split pair.
// v_permlane32_swap_b32 exchanges (vdst's high 32 lanes) <-> (src's low 32
// lanes). Validated end-to-end in rounds 8/9.
template<int RB>
__device__ __forceinline__ void d2b8(const f32x16 &v, bf16x8 &BH, bf16x8 &BL) {
    __bf16 h[8], l[8];
    #pragma unroll
    for (int i = 0; i < 8; ++i) { bfpair p = splitf(v[RB + i]); h[i] = p.h; l[i] = p.l; }
    unsigned ha0 = pk2(h[0], h[1]), ha1 = pk2(h[2], h[3]);
    unsigned hb0 = pk2(h[4], h[5]), hb1 = pk2(h[6], h[7]);
    unsigned la0 = pk2(l[0], l[1]), la1 = pk2(l[2], l[3]);
    unsigned lb0 = pk2(l[4], l[5]), lb1 = pk2(l[6], l[7]);
    asm("v_permlane32_swap_b32 %0, %1" : "+v"(ha0), "+v"(hb0));
    asm("v_permlane32_swap_b32 %0, %1" : "+v"(la0), "+v"(lb0));
    asm("v_permlane32_swap_b32 %0, %1" : "+v"(ha1), "+v"(hb1));
    asm("v_permlane32_swap_b32 %0, %1" : "+v"(la1), "+v"(lb1));
    u32x4 uh = { ha0, ha1, hb0, hb1 };
    u32x4 ul = { la0, la1, lb0, lb1 };
    BH = __builtin_bit_cast(bf16x8, uh);
    BL = __builtin_bit_cast(bf16x8, ul);
}

// ---------------- prep: split + fragment-pack W into workspace ----------------
// frag tid = (((L*8+kc)*4+ot)*2+hi)*32+lane ; elems = W[L][ot*32+lane][kc*16+hi*8+e]
__global__ __launch_bounds__(256) void prep_w(
    const float* __restrict__ Wg, const float* __restrict__ Wd1,
    __bf16* __restrict__ ws)
{
    const int tid  = blockIdx.x * 256 + threadIdx.x;   // 0..8191
    const int lane = tid & 31;
    const int hi   = (tid >> 5) & 1;
    const int ot   = (tid >> 6) & 3;
    const int kc   = (tid >> 8) & 7;
    const int L    = tid >> 11;
    const float* src = ((L < 3) ? (Wg + L * 16384) : Wd1)
                     + (ot * 32 + lane) * 128 + kc * 16 + hi * 8;
    const f32x4 v0 = *(const f32x4*)(src);
    const f32x4 v1 = *(const f32x4*)(src + 4);
    bf16x8 h8, l8;
    #pragma unroll
    for (int e = 0; e < 4; ++e) {
        bfpair p0 = splitf(v0[e]); h8[e]   = p0.h; l8[e]   = p0.l;
        bfpair p1 = splitf(v1[e]); h8[4+e] = p1.h; l8[4+e] = p1.l;
    }
    ((bf16x8*)ws)[tid]        = h8;   // Ph
    ((bf16x8*)ws)[8192 + tid] = l8;   // Pl
}

// ------------------------------- main kernel -------------------------------
__global__ __launch_bounds__(128, 2) void mt_fwd(
    const float* __restrict__ q,   const float* __restrict__ Win, const float* __restrict__ bin,
    const float* __restrict__ bg,  const float* __restrict__ bd1,
    const float* __restrict__ Wd2, const float* __restrict__ bd2,
    const bf16x8* __restrict__ Ph, float* __restrict__ out)
{
    __shared__ __attribute__((aligned(16))) float hb[24 * QP];   // 19968 B

    const int t    = threadIdx.x;
    const int nt   = t >> 6;            // wave: node-tile 0/1
    const int l    = t & 63;
    const int lane = l & 31;
    const int hi   = l >> 5;
    const int n    = nt * 32 + lane;    // this lane's node (col in D)
    const int samp = blockIdx.x;
    const bf16x8* Pl = Ph + 8192;

    const int wq = n * 4;    // own node dword offset within a plane (write)

    // ---- closed-form GCN neighbors (self + 2 lateral(dup x2) + <=2 chain) ----
    int nb[5]; float nw[5];
    {
        const int   fi = n >> 2, js = n & 3;
        const float dg = 5.f + (js > 0 ? 1.f : 0.f) + (js < 3 ? 1.f : 0.f);
        const float di = rsqrtf(dg);
        nb[0] = n;                          nw[0] = di * di;
        nb[1] = ((fi + 12) % 13) * 4 + js;  nw[1] = 2.f * di * di;
        nb[2] = ((fi + 1) % 13) * 4 + js;   nw[2] = 2.f * di * di;
        nb[3] = (js > 0) ? (n - 1) : 0;
        nw[3] = (js > 0) ? di * rsqrtf(6.f + (js > 1 ? 1.f : 0.f)) : 0.f;
        nb[4] = (js < 3) ? (n + 1) : 0;
        nw[4] = (js < 3) ? di * rsqrtf(6.f + (js < 2 ? 1.f : 0.f)) : 0.f;
        if (n >= 52) {
            #pragma unroll
            for (int c = 0; c < 5; ++c) { nb[c] = 0; nw[c] = 0.f; }
        }
    }
    int gq[5];
    #pragma unroll
    for (int c = 0; c < 5; ++c) gq[c] = nb[c] * 4;

    bf16x8 bh[8], bl[8];   // persistent x state (B-frag layout, split)

    // ---------------- encoder: x0 = relu(Win @ q^T + bin), in-reg conversion ----------------
    {
        f32x4 z4; z4[0]=0.f; z4[1]=0.f; z4[2]=0.f; z4[3]=0.f;
        f32x4 u0 = z4, u1 = z4;
        if (hi == 0 && n < 52) {
            const float* qp = q + (samp * 52 + n) * 6;
            const f32x2 a = *(const f32x2*)(qp);
            const f32x2 b = *(const f32x2*)(qp + 2);
            const f32x2 c = *(const f32x2*)(qp + 4);
            u0[0]=a[0]; u0[1]=a[1]; u0[2]=b[0]; u0[3]=b[1]; u1[0]=c[0]; u1[1]=c[1];
        }
        bf16x8 qh, ql;
        #pragma unroll
        for (int e = 0; e < 4; ++e) {
            bfpair p0 = splitf(u0[e]); qh[e]   = p0.h; ql[e]   = p0.l;
            bfpair p1 = splitf(u1[e]); qh[4+e] = p1.h; ql[4+e] = p1.l;
        }

        #pragma unroll
        for (int ot = 0; ot < 4; ++ot) {
            f32x4 v0 = z4, v1 = z4;
            if (hi == 0) {
                const int o_r = ot * 32 + lane;
                const f32x2 a = *(const f32x2*)(Win + o_r * 6);
                const f32x2 b = *(const f32x2*)(Win + o_r * 6 + 2);
                const f32x2 c = *(const f32x2*)(Win + o_r * 6 + 4);
                v0[0]=a[0]; v0[1]=a[1]; v0[2]=b[0]; v0[3]=b[1]; v1[0]=c[0]; v1[1]=c[1];
            }
            bf16x8 ah, al;
            #pragma unroll
            for (int e = 0; e < 4; ++e) {
                bfpair p0 = splitf(v0[e]); ah[e]   = p0.h; al[e]   = p0.l;
                bfpair p1 = splitf(v1[e]); ah[4+e] = p1.h; al[4+e] = p1.l;
            }
            f32x16 acc;
            #pragma unroll
            for (int r = 0; r < 16; ++r) acc[r] = 0.f;
            acc = MFMA(ah, qh, acc);
            acc = MFMA(ah, ql, acc);
            acc = MFMA(al, qh, acc);
            // relu + bias in D regs
            #pragma unroll
            for (int j = 0; j < 4; ++j) {
                const f32x4 bv = *(const f32x4*)(bin + ot * 32 + 8 * j + 4 * hi);
                #pragma unroll
                for (int e = 0; e < 4; ++e) acc[4 * j + e] = fmaxf(acc[4 * j + e] + bv[e], 0.f);
            }
            d2b8<0>(acc, bh[2 * ot],     bl[2 * ot]);
            d2b8<8>(acc, bh[2 * ot + 1], bl[2 * ot + 1]);
        }
    }

    // helpers -----------------------------------------------------------------
    auto mmtile = [&](int fbase, int ot) {
        f32x16 acc;
        #pragma unroll
        for (int r = 0; r < 16; ++r) acc[r] = 0.f;
        #pragma unroll
        for (int kc = 0; kc < 8; ++kc) {
            const int fk = fbase + kc * 256 + ot * 64;
            const bf16x8 wh = Ph[fk];
            const bf16x8 wl = Pl[fk];
            acc = MFMA(wh, bh[kc], acc);
            acc = MFMA(wh, bl[kc], acc);
            acc = MFMA(wl, bh[kc], acc);
        }
        return acc;
    };
    auto wrplanes = [&](const f32x16 &acc, int base) {
        if (n < 52) {
            #pragma unroll
            for (int j = 0; j < 4; ++j) {
                f32x4 v = { acc[4*j+0], acc[4*j+1], acc[4*j+2], acc[4*j+3] };
                *(f32x4*)&hb[(base + 2 * j + hi) * QP + wq] = v;
            }
        }
    };
    // gather + state update for one kc, reading planes p0, p0+1
    auto gatherKc = [&](int kc, int p0, const float* bsrc) {
        f32x4 t0, t1;
        #pragma unroll
        for (int e = 0; e < 4; ++e) { t0[e] = 0.f; t1[e] = 0.f; }
        #pragma unroll
        for (int c = 0; c < 5; ++c) {
            t0 += nw[c] * *(const f32x4*)&hb[p0 * QP + gq[c]];
            t1 += nw[c] * *(const f32x4*)&hb[(p0 + 1) * QP + gq[c]];
        }
        const f32x4 b0 = *(const f32x4*)(bsrc + kc * 16 + 8 * hi);
        const f32x4 b1 = *(const f32x4*)(bsrc + kc * 16 + 8 * hi + 4);
        #pragma unroll
        for (int e = 0; e < 4; ++e) {
            {
                const float xo = (float)bh[kc][e] + (float)bl[kc][e];
                const float xn = xo + fmaxf(t0[e] + b0[e], 0.f);
                bfpair p = splitf(xn); bh[kc][e] = p.h; bl[kc][e] = p.l;
            }
            {
                const float xo = (float)bh[kc][4+e] + (float)bl[kc][4+e];
                const float xn = xo + fmaxf(t1[e] + b1[e], 0.f);
                bfpair p = splitf(xn); bh[kc][4+e] = p.h; bl[kc][4+e] = p.l;
            }
        }
    };

    // ------------------- 3 GNN layers (24-plane deferred schedule) -------------------
    #pragma unroll 1
    for (int L = 0; L < 3; ++L) {
        const int fbase = L * 2048 + hi * 32 + lane;
        const float* bsrc = bg + L * 128;

        // mmA: ot 0,1,2 -> planes 0-7, 8-15, 16-23
        {
            f32x16 a0 = mmtile(fbase, 0); wrplanes(a0, 0);
            f32x16 a1 = mmtile(fbase, 1); wrplanes(a1, 8);
            f32x16 a2 = mmtile(fbase, 2); wrplanes(a2, 16);
        }
        __syncthreads();                         // bar1: planes 0-23 visible

        // mm ot3 held (old x fully consumed after this)
        f32x16 a3 = mmtile(fbase, 3);

        // gatherA: kc 0..5 (planes 4kc+2hi, +1), update state
        #pragma unroll
        for (int kc = 0; kc < 6; ++kc) gatherKc(kc, 4 * kc + 2 * hi, bsrc);
        __syncthreads();                         // bar2: gatherA reads done

        wrplanes(a3, 0);                         // ot3 -> planes 0-7 (reuse)
        __syncthreads();                         // bar3: ot3 planes visible

        // gatherB: kc 6,7 (planes 4kc+2hi-24, +1)
        gatherKc(6, 2 * hi,     bsrc);
        gatherKc(7, 4 + 2 * hi, bsrc);
        __syncthreads();                         // bar4: gatherB reads done
    }

    // ------------- decoder fused: out^T = Wd2 @ relu(Wd1@x + bd1)^T + bd2 -------------
    {
        const int fbase = 3 * 2048 + hi * 32 + lane;
        f32x16 acc2;
        #pragma unroll
        for (int r = 0; r < 16; ++r) acc2[r] = 0.f;
        f32x4 z4; z4[0]=0.f; z4[1]=0.f; z4[2]=0.f; z4[3]=0.f;

        #pragma unroll
        for (int ot = 0; ot < 4; ++ot) {
            f32x16 a = mmtile(fbase, ot);
            #pragma unroll
            for (int j = 0; j < 4; ++j) {
                const f32x4 bv = *(const f32x4*)(bd1 + ot * 32 + 8 * j + 4 * hi);
                #pragma unroll
                for (int e = 0; e < 4; ++e) a[4 * j + e] = fmaxf(a[4 * j + e] + bv[e], 0.f);
            }
            bf16x8 yh0, yl0, yh1, yl1;
            d2b8<0>(a, yh0, yl0);   // y B-frag kc = 2ot
            d2b8<8>(a, yh1, yl1);   // y B-frag kc = 2ot+1
            // decoder-2 partial sums for these two k-chunks
            #pragma unroll
            for (int kk = 0; kk < 2; ++kk) {
                const int kc = 2 * ot + kk;
                const int kb = kc * 16 + 8 * hi;
                f32x4 w0 = z4, w1 = z4;
                if (lane < 6) {
                    const float* wp = Wd2 + lane * 128 + kb;
                    w0 = *(const f32x4*)(wp);
                    w1 = *(const f32x4*)(wp + 4);
                }
                bf16x8 ah, al;
                #pragma unroll
                for (int e = 0; e < 4; ++e) {
                    bfpair p0 = splitf(w0[e]); ah[e]   = p0.h; al[e]   = p0.l;
                    bfpair p1 = splitf(w1[e]); ah[4+e] = p1.h; al[4+e] = p1.l;
                }
                const bf16x8 yh = kk ? yh1 : yh0;
                const bf16x8 yl = kk ? yl1 : yl0;
                acc2 = MFMA(ah, yh, acc2);
                acc2 = MFMA(ah, yl, acc2);
                acc2 = MFMA(al, yh, acc2);
            }
        }
        if (n < 52) {
            float* op = out + (samp * 52 + n) * 6;
            if (hi == 0) {
                #pragma unroll
                for (int r = 0; r < 4; ++r) op[r] = acc2[r] + bd2[r];          // f = r
            } else {
                #pragma unroll
                for (int r = 0; r < 2; ++r) op[4 + r] = acc2[r] + bd2[4 + r];  // f = 4+r
            }
        }
    }
}

extern "C" void kernel_launch(void* const* d_in, const int* in_sizes, int n_in,
                              void* d_out, int out_size, void* d_ws, size_t ws_size,
                              hipStream_t stream) {
    (void)in_sizes; (void)n_in; (void)ws_size; (void)out_size;
    const float* q   = (const float*)d_in[0];
    const float* Win = (const float*)d_in[1];
    const float* bin = (const float*)d_in[2];
    const float* Wg  = (const float*)d_in[3];
    const float* bg  = (const float*)d_in[4];
    const float* Wd1 = (const float*)d_in[5];
    const float* bd1 = (const float*)d_in[6];
    const float* Wd2 = (const float*)d_in[7];
    const float* bd2 = (const float*)d_in[8];
    float* out = (float*)d_out;

    prep_w<<<32, 256, 0, stream>>>(Wg, Wd1, (__bf16*)d_ws);
    mt_fwd<<<4096, 128, 0, stream>>>(q, Win, bin, bg, bd1, Wd2, bd2,
                                     (const bf16x8*)d_ws, out);
}

// Round 12
// 168.728 us; speedup vs baseline: 2.6953x; 2.6953x over previous
//
#include <hip/hip_runtime.h>

// MicrotubuleDynamicsModel fused forward, round 12 (r11 + compile fix):
// Round-6 proven schedule (84 VGPR, no held accs, 2 barriers/layer) with the
// h-mirror switched to fp16 octet-planes:
//   hx[16 octets][52 nodes][8 fp16] = 13312 B  -> 12 blocks/CU, 24 waves.
//   octet m = 2kc+hi is exactly one thread's B-frag feature slice, so the
//   gather is ONE b128 per neighbor per kc (was two) and writes are b64.
// Store-only fp16 (t accumulated in fp32); x state stays as split bf16 pair
// in regs; encoder converts D->B in-reg via permlane32_swap.

typedef __attribute__((ext_vector_type(2)))  float  f32x2;
typedef __attribute__((ext_vector_type(4)))  float  f32x4;
typedef __attribute__((ext_vector_type(16))) float  f32x16;
typedef __attribute__((ext_vector_type(8)))  __bf16 bf16x8;
typedef __attribute__((ext_vector_type(4)))  unsigned int u32x4;
typedef __attribute__((ext_vector_type(4)))  _Float16 h16x4;
typedef __attribute__((ext_vector_type(8)))  _Float16 h16x8;

#define MFMA(a, b, c) __builtin_amdgcn_mfma_f32_32x32x16_bf16((a), (b), (c), 0, 0, 0)

struct bfpair { __bf16 h, l; };
__device__ __forceinline__ bfpair splitf(float f) {
    bfpair p;
    p.h = (__bf16)f;               // RTN
    p.l = (__bf16)(f - (float)p.h);
    return p;
}
__device__ __forceinline__ unsigned pk2(__bf16 a, __bf16 b) {
    return (unsigned)__builtin_bit_cast(unsigned short, a)
         | ((unsigned)__builtin_bit_cast(unsigned short, b) << 16);
}
__device__ __forceinline__ unsigned pkrtz(float a, float b) {
    return __builtin_bit_cast(unsigned, __builtin_amdgcn_cvt_pkrtz(a, b));
}

// D-layout k-chunk (regs RB..RB+7) -> B-frag split pair via permlane32_swap.
// Validated end-to-end rounds 8-10.
template<int RB>
__device__ __forceinline__ void d2b8(const f32x16 &v, bf16x8 &BH, bf16x8 &BL) {
    __bf16 h[8], l[8];
    #pragma unroll
    for (int i = 0; i < 8; ++i) { bfpair p = splitf(v[RB + i]); h[i] = p.h; l[i] = p.l; }
    unsigned ha0 = pk2(h[0], h[1]), ha1 = pk2(h[2], h[3]);
    unsigned hb0 = pk2(h[4], h[5]), hb1 = pk2(h[6], h[7]);
    unsigned la0 = pk2(l[0], l[1]), la1 = pk2(l[2], l[3]);
    unsigned lb0 = pk2(l[4], l[5]), lb1 = pk2(l[6], l[7]);
    asm("v_permlane32_swap_b32 %0, %1" : "+v"(ha0), "+v"(hb0));
    asm("v_permlane32_swap_b32 %0, %1" : "+v"(la0), "+v"(lb0));
    asm("v_permlane32_swap_b32 %0, %1" : "+v"(ha1), "+v"(hb1));
    asm("v_permlane32_swap_b32 %0, %1" : "+v"(la1), "+v"(lb1));
    u32x4 uh = { ha0, ha1, hb0, hb1 };
    u32x4 ul = { la0, la1, lb0, lb1 };
    BH = __builtin_bit_cast(bf16x8, uh);
    BL = __builtin_bit_cast(bf16x8, ul);
}

// ---------------- prep: split + fragment-pack W into workspace ----------------
// frag tid = (((L*8+kc)*4+ot)*2+hi)*32+lane ; elems = W[L][ot*32+lane][kc*16+hi*8+e]
__global__ __launch_bounds__(256) void prep_w(
    const float* __restrict__ Wg, const float* __restrict__ Wd1,
    __bf16* __restrict__ ws)
{
    const int tid  = blockIdx.x * 256 + threadIdx.x;   // 0..8191
    const int lane = tid & 31;
    const int hi   = (tid >> 5) & 1;
    const int ot   = (tid >> 6) & 3;
    const int kc   = (tid >> 8) & 7;
    const int L    = tid >> 11;
    const float* src = ((L < 3) ? (Wg + L * 16384) : Wd1)
                     + (ot * 32 + lane) * 128 + kc * 16 + hi * 8;
    const f32x4 v0 = *(const f32x4*)(src);
    const f32x4 v1 = *(const f32x4*)(src + 4);
    bf16x8 h8, l8;
    #pragma unroll
    for (int e = 0; e < 4; ++e) {
        bfpair p0 = splitf(v0[e]); h8[e]   = p0.h; l8[e]   = p0.l;
        bfpair p1 = splitf(v1[e]); h8[4+e] = p1.h; l8[4+e] = p1.l;
    }
    ((bf16x8*)ws)[tid]        = h8;   // Ph
    ((bf16x8*)ws)[8192 + tid] = l8;   // Pl
}

// ------------------------------- main kernel -------------------------------
__global__ __launch_bounds__(128, 3) void mt_fwd(
    const float* __restrict__ q,   const float* __restrict__ Win, const float* __restrict__ bin,
    const float* __restrict__ bg,  const float* __restrict__ bd1,
    const float* __restrict__ Wd2, const float* __restrict__ bd2,
    const bf16x8* __restrict__ Ph, float* __restrict__ out)
{
    __shared__ __attribute__((aligned(16))) _Float16 hx[16 * 52 * 8];  // 13312 B

    const int t    = threadIdx.x;
    const int nt   = t >> 6;            // wave: node-tile 0/1
    const int l    = t & 63;
    const int lane = l & 31;
    const int hi   = l >> 5;
    const int n    = nt * 32 + lane;    // this lane's node (col in D)
    const int nc   = (n < 52) ? n : 0;
    const int samp = blockIdx.x;
    const bf16x8* Pl = Ph + 8192;

    // ---- closed-form GCN neighbors (self + 2 lateral(dup x2) + <=2 chain) ----
    int nb[5]; float nw[5];
    {
        const int   fi = n >> 2, js = n & 3;
        const float dg = 5.f + (js > 0 ? 1.f : 0.f) + (js < 3 ? 1.f : 0.f);
        const float di = rsqrtf(dg);
        nb[0] = n;                          nw[0] = di * di;
        nb[1] = ((fi + 12) % 13) * 4 + js;  nw[1] = 2.f * di * di;
        nb[2] = ((fi + 1) % 13) * 4 + js;   nw[2] = 2.f * di * di;
        nb[3] = (js > 0) ? (n - 1) : 0;
        nw[3] = (js > 0) ? di * rsqrtf(6.f + (js > 1 ? 1.f : 0.f)) : 0.f;
        nb[4] = (js < 3) ? (n + 1) : 0;
        nw[4] = (js < 3) ? di * rsqrtf(6.f + (js < 2 ? 1.f : 0.f)) : 0.f;
        if (n >= 52) {
            #pragma unroll
            for (int c = 0; c < 5; ++c) { nb[c] = 0; nw[c] = 0.f; }
        }
    }

    bf16x8 bh[8], bl[8];   // persistent x state (B-frag layout, split)

    // ---------------- encoder: x0 = relu(Win @ q^T + bin), in-reg conversion ----------------
    {
        f32x4 z4; z4[0]=0.f; z4[1]=0.f; z4[2]=0.f; z4[3]=0.f;
        f32x4 u0 = z4, u1 = z4;
        if (hi == 0 && n < 52) {
            const float* qp = q + (samp * 52 + n) * 6;
            const f32x2 a = *(const f32x2*)(qp);
            const f32x2 b = *(const f32x2*)(qp + 2);
            const f32x2 c = *(const f32x2*)(qp + 4);
            u0[0]=a[0]; u0[1]=a[1]; u0[2]=b[0]; u0[3]=b[1]; u1[0]=c[0]; u1[1]=c[1];
        }
        bf16x8 qh, ql;
        #pragma unroll
        for (int e = 0; e < 4; ++e) {
            bfpair p0 = splitf(u0[e]); qh[e]   = p0.h; ql[e]   = p0.l;
            bfpair p1 = splitf(u1[e]); qh[4+e] = p1.h; ql[4+e] = p1.l;
        }

        #pragma unroll
        for (int ot = 0; ot < 4; ++ot) {
            f32x4 v0 = z4, v1 = z4;
            if (hi == 0) {
                const int o_r = ot * 32 + lane;
                const f32x2 a = *(const f32x2*)(Win + o_r * 6);
                const f32x2 b = *(const f32x2*)(Win + o_r * 6 + 2);
                const f32x2 c = *(const f32x2*)(Win + o_r * 6 + 4);
                v0[0]=a[0]; v0[1]=a[1]; v0[2]=b[0]; v0[3]=b[1]; v1[0]=c[0]; v1[1]=c[1];
            }
            bf16x8 ah, al;
            #pragma unroll
            for (int e = 0; e < 4; ++e) {
                bfpair p0 = splitf(v0[e]); ah[e]   = p0.h; al[e]   = p0.l;
                bfpair p1 = splitf(v1[e]); ah[4+e] = p1.h; al[4+e] = p1.l;
            }
            f32x16 acc;
            #pragma unroll
            for (int r = 0; r < 16; ++r) acc[r] = 0.f;
            acc = MFMA(ah, qh, acc);
            acc = MFMA(ah, ql, acc);
            acc = MFMA(al, qh, acc);
            #pragma unroll
            for (int j = 0; j < 4; ++j) {
                const f32x4 bv = *(const f32x4*)(bin + ot * 32 + 8 * j + 4 * hi);
                #pragma unroll
                for (int e = 0; e < 4; ++e) acc[4 * j + e] = fmaxf(acc[4 * j + e] + bv[e], 0.f);
            }
            d2b8<0>(acc, bh[2 * ot],     bl[2 * ot]);
            d2b8<8>(acc, bh[2 * ot + 1], bl[2 * ot + 1]);
        }
    }

    // helpers -----------------------------------------------------------------
    auto mmtile = [&](int fbase, int ot) {
        f32x16 acc;
        #pragma unroll
        for (int r = 0; r < 16; ++r) acc[r] = 0.f;
        #pragma unroll
        for (int kc = 0; kc < 8; ++kc) {
            const int fk = fbase + kc * 256 + ot * 64;
            const bf16x8 wh = Ph[fk];
            const bf16x8 wl = Pl[fk];
            acc = MFMA(wh, bh[kc], acc);
            acc = MFMA(wh, bl[kc], acc);
            acc = MFMA(wl, bh[kc], acc);
        }
        return acc;
    };
    // write D-tile ot to fp16 octet planes: octet = ot*4+j, halves [4hi..4hi+3]
    auto wrOct = [&](const f32x16 &acc, int ot) {
        if (n < 52) {
            #pragma unroll
            for (int j = 0; j < 4; ++j) {
                unsigned lo = pkrtz(acc[4*j+0], acc[4*j+1]);
                unsigned hi2 = pkrtz(acc[4*j+2], acc[4*j+3]);
                unsigned long long v = (unsigned long long)lo | ((unsigned long long)hi2 << 32);
                *(unsigned long long*)&hx[((ot * 4 + j) * 52 + n) * 8 + hi * 4] = v;
            }
        }
    };

    // ------------------- 3 GNN layers (r6 schedule, fp16 mirror) -------------------
    #pragma unroll 1
    for (int L = 0; L < 3; ++L) {
        const int fbase = L * 2048 + hi * 32 + lane;
        const float* bsrc = bg + L * 128;

        // mm all 4 ot -> write octet planes
        {
            f32x16 a0 = mmtile(fbase, 0); wrOct(a0, 0);
            f32x16 a1 = mmtile(fbase, 1); wrOct(a1, 1);
            f32x16 a2 = mmtile(fbase, 2); wrOct(a2, 2);
            f32x16 a3 = mmtile(fbase, 3); wrOct(a3, 3);
        }
        __syncthreads();    // planes visible

        // gather t = A@h + state update, per kc (octet m = 2kc+hi = B-frag slice)
        #pragma unroll
        for (int kc = 0; kc < 8; ++kc) {
            const int m = 2 * kc + hi;
            float tt[8] = {0.f,0.f,0.f,0.f,0.f,0.f,0.f,0.f};
            #pragma unroll
            for (int c = 0; c < 5; ++c) {
                const h16x8 hv = *(const h16x8*)&hx[(m * 52 + nb[c]) * 8];
                const float w = nw[c];
                #pragma unroll
                for (int e = 0; e < 8; ++e) tt[e] += w * (float)hv[e];
            }
            const f32x4 b0 = *(const f32x4*)(bsrc + kc * 16 + 8 * hi);
            const f32x4 b1 = *(const f32x4*)(bsrc + kc * 16 + 8 * hi + 4);
            #pragma unroll
            for (int e = 0; e < 4; ++e) {
                {
                    const float xo = (float)bh[kc][e] + (float)bl[kc][e];
                    const float xn = xo + fmaxf(tt[e] + b0[e], 0.f);
                    bfpair p = splitf(xn); bh[kc][e] = p.h; bl[kc][e] = p.l;
                }
                {
                    const float xo = (float)bh[kc][4+e] + (float)bl[kc][4+e];
                    const float xn = xo + fmaxf(tt[4+e] + b1[e], 0.f);
                    bfpair p = splitf(xn); bh[kc][4+e] = p.h; bl[kc][4+e] = p.l;
                }
            }
        }
        __syncthreads();    // gather reads done before next layer's writes
    }

    // ---------------- decoder-1: y = relu(x @ Wd1^T + bd1), fp16 bounce ----------------
    {
        const int fbase = 3 * 2048 + hi * 32 + lane;
        {
            f32x16 a0 = mmtile(fbase, 0);
            #pragma unroll
            for (int j = 0; j < 4; ++j) {
                const f32x4 bv = *(const f32x4*)(bd1 + 0 * 32 + 8 * j + 4 * hi);
                #pragma unroll
                for (int e = 0; e < 4; ++e) a0[4*j+e] = fmaxf(a0[4*j+e] + bv[e], 0.f);
            }
            wrOct(a0, 0);
            f32x16 a1 = mmtile(fbase, 1);
            #pragma unroll
            for (int j = 0; j < 4; ++j) {
                const f32x4 bv = *(const f32x4*)(bd1 + 1 * 32 + 8 * j + 4 * hi);
                #pragma unroll
                for (int e = 0; e < 4; ++e) a1[4*j+e] = fmaxf(a1[4*j+e] + bv[e], 0.f);
            }
            wrOct(a1, 1);
            f32x16 a2 = mmtile(fbase, 2);
            #pragma unroll
            for (int j = 0; j < 4; ++j) {
                const f32x4 bv = *(const f32x4*)(bd1 + 2 * 32 + 8 * j + 4 * hi);
                #pragma unroll
                for (int e = 0; e < 4; ++e) a2[4*j+e] = fmaxf(a2[4*j+e] + bv[e], 0.f);
            }
            wrOct(a2, 2);
            f32x16 a3 = mmtile(fbase, 3);
            #pragma unroll
            for (int j = 0; j < 4; ++j) {
                const f32x4 bv = *(const f32x4*)(bd1 + 3 * 32 + 8 * j + 4 * hi);
                #pragma unroll
                for (int e = 0; e < 4; ++e) a3[4*j+e] = fmaxf(a3[4*j+e] + bv[e], 0.f);
            }
            wrOct(a3, 3);
        }
        __syncthreads();
        // readback own octets -> y state (B-frag layout)
        #pragma unroll
        for (int kc = 0; kc < 8; ++kc) {
            const int m = 2 * kc + hi;
            const h16x8 hv = *(const h16x8*)&hx[(m * 52 + nc) * 8];
            #pragma unroll
            for (int e = 0; e < 4; ++e) {
                bfpair p0 = splitf((float)hv[e]);   bh[kc][e]   = p0.h; bl[kc][e]   = p0.l;
                bfpair p1 = splitf((float)hv[4+e]); bh[kc][4+e] = p1.h; bl[kc][4+e] = p1.l;
            }
        }
    }

    // ---------------- decoder-2: out^T = Wd2 @ y^T + bd2 ----------------
    {
        f32x16 acc;
        #pragma unroll
        for (int r = 0; r < 16; ++r) acc[r] = 0.f;
        f32x4 z4; z4[0]=0.f; z4[1]=0.f; z4[2]=0.f; z4[3]=0.f;

        #pragma unroll
        for (int kc = 0; kc < 8; ++kc) {
            const int kb = kc * 16 + 8 * hi;
            f32x4 w0 = z4, w1 = z4;
            if (lane < 6) {
                const float* wp = Wd2 + lane * 128 + kb;
                w0 = *(const f32x4*)(wp);
                w1 = *(const f32x4*)(wp + 4);
            }
            bf16x8 ah, al;
            #pragma unroll
            for (int e = 0; e < 4; ++e) {
                bfpair p0 = splitf(w0[e]); ah[e]   = p0.h; al[e]   = p0.l;
                bfpair p1 = splitf(w1[e]); ah[4+e] = p1.h; al[4+e] = p1.l;
            }
            acc = MFMA(ah, bh[kc], acc);
            acc = MFMA(ah, bl[kc], acc);
            acc = MFMA(al, bh[kc], acc);
        }
        if (n < 52) {
            float* op = out + (samp * 52 + n) * 6;
            if (hi == 0) {
                #pragma unroll
                for (int r = 0; r < 4; ++r) op[r] = acc[r] + bd2[r];          // f = r
            } else {
                #pragma unroll
                for (int r = 0; r < 2; ++r) op[4 + r] = acc[r] + bd2[4 + r];  // f = 4+r
            }
        }
    }
}

extern "C" void kernel_launch(void* const* d_in, const int* in_sizes, int n_in,
                              void* d_out, int out_size, void* d_ws, size_t ws_size,
                              hipStream_t stream) {
    (void)in_sizes; (void)n_in; (void)ws_size; (void)out_size;
    const float* q   = (const float*)d_in[0];
    const float* Win = (const float*)d_in[1];
    const float* bin = (const float*)d_in[2];
    const float* Wg  = (const float*)d_in[3];
    const float* bg  = (const float*)d_in[4];
    const float* Wd1 = (const float*)d_in[5];
    const float* bd1 = (const float*)d_in[6];
    const float* Wd2 = (const float*)d_in[7];
    const float* bd2 = (const float*)d_in[8];
    float* out = (float*)d_out;

    prep_w<<<32, 256, 0, stream>>>(Wg, Wd1, (__bf16*)d_ws);
    mt_fwd<<<4096, 128, 0, stream>>>(q, Win, bin, bg, bd1, Wd2, bd2,
                                     (const bf16x8*)d_ws, out);
}